// Round 5
// baseline (2706.248 us; speedup 1.0000x reference)
//
#include <hip/hip_runtime.h>
#include <math.h>

constexpr int NY_ = 320, NX_ = 320, NT_ = 160, SHOTS_ = 2, NSRC_ = 8, NREC_ = 96;
constexpr float DT_  = 4.0e-4f;
constexpr float C1_  = 9.0f / 8.0f;
constexpr float C2_  = -1.0f / 24.0f;
constexpr float IDH_ = 0.25f;           // 1/DH, exact
constexpr int NP_     = NY_ * NX_;
constexpr int NSTRIP_ = 40;             // 8-row strips per shot
constexpr int NBLK_   = SHOTS_ * NSTRIP_;
constexpr int NR_     = NT_ / 2;        // 80 rounds, 2 timesteps per round
constexpr int PK_     = 128;            // packed x-CPML row width (cols 0..63 | 256..319)
// ws layout (float words): full-grid ping-pong mirrors of everything a neighbor needs
constexpr int SG_OFF_  = 0;                                   // [b2][f3:syy,sxy,sxx][s2][NP]
constexpr int VG_OFF_  = SG_OFF_  + 2 * 3 * SHOTS_ * NP_;     // [b2][f2:vy,vx][s2][NP]
constexpr int MSF_OFF_ = VG_OFF_  + 2 * 2 * SHOTS_ * NP_;     // [b2][f2:msyyy,msxyy][s2][NP]
constexpr int MSP_OFF_ = MSF_OFF_ + 2 * 2 * SHOTS_ * NP_;     // [b2][f2:msxyx,msxxx][s2][NY*PK]
constexpr int MVF_OFF_ = MSP_OFF_ + 2 * 2 * SHOTS_ * NY_ * PK_; // [b2][f2:mvyy,mvxy][s2][NP]
constexpr int MVP_OFF_ = MVF_OFF_ + 2 * 2 * SHOTS_ * NP_;     // [b2][f2:mvyx,mvxx][s2][NY*PK]
constexpr int REC_OFF_ = MVP_OFF_ + 2 * 2 * SHOTS_ * NY_ * PK_;
constexpr int FLG_OFF_ = REC_OFF_ + SHOTS_ * NREC_ * NT_;
constexpr int WS_WORDS_ = FLG_OFF_ + 128;                     // ~17.5 MB total

// ---- coherent (IF-backed) access: relaxed agent-scope atomics ----
__device__ __forceinline__ float cld(const float* p) {
    return __hip_atomic_load(p, __ATOMIC_RELAXED, __HIP_MEMORY_SCOPE_AGENT);
}
__device__ __forceinline__ void cst(float* p, float v) {
    __hip_atomic_store(p, v, __ATOMIC_RELAXED, __HIP_MEMORY_SCOPE_AGENT);
}
__device__ __forceinline__ unsigned cldu(const unsigned* p) {
    return __hip_atomic_load(p, __ATOMIC_RELAXED, __HIP_MEMORY_SCOPE_AGENT);
}
__device__ __forceinline__ void cstu(unsigned* p, unsigned v) {
    __hip_atomic_store(p, v, __ATOMIC_RELAXED, __HIP_MEMORY_SCOPE_AGENT);
}

// guarded global halo load: out-of-grid rows read 0 (== masked border equivalence)
__device__ __forceinline__ float gldf(const float* p, int y, int c) {
    return ((unsigned)y < (unsigned)NY_) ? cld(p + y * NX_ + c) : 0.0f;
}
// guarded LDS x-tap: out-of-grid cols read 0
__device__ __forceinline__ float ltap(float (*A)[NX_], int ly, int c) {
    return ((unsigned)c < (unsigned)NX_) ? A[ly][c] : 0.0f;
}

// ws mirror pointers
__device__ __forceinline__ float* SGp (float* ws, int b, int f, int s) { return ws + SG_OFF_  + ((b * 3 + f) * SHOTS_ + s) * NP_; }
__device__ __forceinline__ float* VGp (float* ws, int b, int f, int s) { return ws + VG_OFF_  + ((b * 2 + f) * SHOTS_ + s) * NP_; }
__device__ __forceinline__ float* MSfp(float* ws, int b, int f, int s) { return ws + MSF_OFF_ + ((b * 2 + f) * SHOTS_ + s) * NP_; }
__device__ __forceinline__ float* MSpp(float* ws, int b, int f, int s) { return ws + MSP_OFF_ + ((b * 2 + f) * SHOTS_ + s) * NY_ * PK_; }
__device__ __forceinline__ float* MVfp(float* ws, int b, int f, int s) { return ws + MVF_OFF_ + ((b * 2 + f) * SHOTS_ + s) * NP_; }
__device__ __forceinline__ float* MVpp(float* ws, int b, int f, int s) { return ws + MVP_OFF_ + ((b * 2 + f) * SHOTS_ + s) * NY_ * PK_; }

// P2P neighbor sync (verified pattern)
__device__ __forceinline__ void pollNbr(const unsigned* f, int sbase, int j,
                                        unsigned tgt, int tid) {
    __syncthreads();
    if (tid < 64) {
        for (;;) {
            bool ok = true;
            if (tid == 0 && j > 0)                ok = cldu(&f[sbase + j - 1]) >= tgt;
            else if (tid == 1 && j < NSTRIP_ - 1) ok = cldu(&f[sbase + j + 1]) >= tgt;
            if (__all(ok)) break;
            __builtin_amdgcn_s_sleep(1);
        }
    }
    __syncthreads();
    asm volatile("" ::: "memory");
}

__device__ __forceinline__ float pml_by(int gy) {
    const double d0 = 3.0 * 1600.0 * log(1000.0) / (2.0 * 20.0 * 4.0);
    double py = 0.0;
    if (gy < 20)             { double u = (20.0 - gy) / 20.0;           py = u * u; }
    else if (gy >= NY_ - 20) { double u = (gy - (NY_ - 1 - 20)) / 20.0; py = u * u; }
    return (float)exp(-d0 * py * 4.0e-4);
}

__device__ __forceinline__ unsigned long long srcmask(const int* __restrict__ src_loc,
                                                      int s, int gy, int lane) {
    unsigned long long sm = 0ull;
    if ((unsigned)gy < (unsigned)NY_) {
        for (int js = 0; js < NSRC_; ++js) {
            int sy = src_loc[(s * NSRC_ + js) * 2 + 0];
            int sx = src_loc[(s * NSRC_ + js) * 2 + 1];
            if (sy == gy && (sx & 63) == lane) sm |= 1ull << (8 * (sx >> 6) + js);
        }
    }
    return sm;
}

// x-CPML static sparsity: groups k=1,2,3 (cols 64..255) have bx=1 -> memory vars
// stay exactly 0 forever -> packed [2] arrays hold only k=0,k=4. Bit-exact.

// ---- velocity update of LDS row y (in place); CPML state in registers ----
template<bool PUB>
__device__ __forceinline__ void vrowL(
    int lane, int y, const float* __restrict__ ampsT,
    float (&ms1)[5], float (&ms2)[5], float (&ms3)[2], float (&ms4)[2],  // msyyy,msxyy,msxyx,msxxx
    float by, const float (&bx2)[2], const float (&bxm12)[2],
    const float* __restrict__ buRow, float mr, const float (&mkc2)[2],
    unsigned long long sm,
    float (*Lsyy)[NX_], float (*Lsxy)[NX_], float (*Lsxx)[NX_],
    float (*Lvy)[NX_], float (*Lvx)[NX_],
    float* pubVy, float* pubVx)
{
    const int iS = y + 8, iV = y + 6;
    const float bym1 = by - 1.0f;
    #pragma unroll
    for (int k = 0; k < 5; ++k) {
        const int c = 64 * k + lane;
        const bool px = (k == 0 || k == 4);
        const int xk = (k == 0) ? 0 : 1;
        const float mk = mr * (px ? mkc2[xk] : 1.0f);
        const float buk = buRow[c];
        // D-_y(syy)
        float d = (C1_ * (Lsyy[iS][c] - Lsyy[iS - 1][c])
                 + C2_ * (Lsyy[iS + 1][c] - Lsyy[iS - 2][c])) * IDH_;
        ms1[k] = by * ms1[k] + bym1 * d;
        float ay = d + ms1[k];
        // D+_x(sxy)
        d = (C1_ * (ltap(Lsxy, iS, c + 1) - Lsxy[iS][c])
           + C2_ * (ltap(Lsxy, iS, c + 2) - ltap(Lsxy, iS, c - 1))) * IDH_;
        if (px) { ms3[xk] = bx2[xk] * ms3[xk] + bxm12[xk] * d; ay += d + ms3[xk]; }
        else    { ay += d; }
        float vy = Lvy[iV][c] + DT_ * buk * ay;
        unsigned m = (unsigned)(sm >> (8 * k)) & 0xFFu;
        if (m) {
            for (int js = 0; js < NSRC_; ++js)
                if (m & (1u << js)) vy += DT_ * ampsT[js * NT_] * buk;
        }
        vy *= mk;
        Lvy[iV][c] = vy;
        if (PUB) cst(pubVy + c, vy);
        // D-_x(sxx)
        d = (C1_ * (Lsxx[iV][c] - ltap(Lsxx, iV, c - 1))
           + C2_ * (ltap(Lsxx, iV, c + 1) - ltap(Lsxx, iV, c - 2))) * IDH_;
        float ax;
        if (px) { ms4[xk] = bx2[xk] * ms4[xk] + bxm12[xk] * d; ax = d + ms4[xk]; }
        else    { ax = d; }
        // D+_y(sxy)
        d = (C1_ * (Lsxy[iS + 1][c] - Lsxy[iS][c])
           + C2_ * (Lsxy[iS + 2][c] - Lsxy[iS - 1][c])) * IDH_;
        ms2[k] = by * ms2[k] + bym1 * d;
        ax += d + ms2[k];
        float vx = (Lvx[iV][c] + DT_ * buk * ax) * mk;
        Lvx[iV][c] = vx;
        if (PUB) cst(pubVx + c, vx);
    }
}

// ---- stress update of LDS row y (in place); CPML state in registers ----
template<bool PUB>
__device__ __forceinline__ void srowL(
    int lane, int y,
    float (&mv1)[5], float (&mv2)[2], float (&mv3)[5], float (&mv4)[2],  // mvyy,mvyx,mvxy,mvxx
    float by, const float (&bx2)[2], const float (&bxm12)[2],
    const float* __restrict__ laRow, const float* __restrict__ muRow,
    float mr, const float (&mkc2)[2],
    float (*Lsyy)[NX_], float (*Lsxy)[NX_], float (*Lsxx)[NX_],
    float (*Lvy)[NX_], float (*Lvx)[NX_],
    float* pubYY, float* pubXY, float* pubXX)
{
    const int iS = y + 8, iV = y + 6;
    const float bym1 = by - 1.0f;
    #pragma unroll
    for (int k = 0; k < 5; ++k) {
        const int c = 64 * k + lane;
        const bool px = (k == 0 || k == 4);
        const int xk = (k == 0) ? 0 : 1;
        const float mk = mr * (px ? mkc2[xk] : 1.0f);
        const float lak = laRow[c];
        const float muk = muRow[c];
        // D+_y(vy)
        float d = (C1_ * (Lvy[iV + 1][c] - Lvy[iV][c])
                 + C2_ * (Lvy[iV + 2][c] - Lvy[iV - 1][c])) * IDH_;
        mv1[k] = by * mv1[k] + bym1 * d;
        float e1 = d + mv1[k];
        // D-_x(vx)
        d = (C1_ * (Lvx[iV][c] - ltap(Lvx, iV, c - 1))
           + C2_ * (ltap(Lvx, iV, c + 1) - ltap(Lvx, iV, c - 2))) * IDH_;
        float e2;
        if (px) { mv4[xk] = bx2[xk] * mv4[xk] + bxm12[xk] * d; e2 = d + mv4[xk]; }
        else    { e2 = d; }
        const float l2m = lak + 2.0f * muk;
        float syy = (Lsyy[iS][c] + DT_ * (l2m * e1 + lak * e2)) * mk;
        float sxx = (Lsxx[iV][c] + DT_ * (l2m * e2 + lak * e1)) * mk;
        Lsyy[iS][c] = syy; Lsxx[iV][c] = sxx;
        // D+_x(vy)
        d = (C1_ * (ltap(Lvy, iV, c + 1) - Lvy[iV][c])
           + C2_ * (ltap(Lvy, iV, c + 2) - ltap(Lvy, iV, c - 1))) * IDH_;
        float g;
        if (px) { mv2[xk] = bx2[xk] * mv2[xk] + bxm12[xk] * d; g = d + mv2[xk]; }
        else    { g = d; }
        // D-_y(vx)
        d = (C1_ * (Lvx[iV][c] - Lvx[iV - 1][c]) + C2_ * (Lvx[iV + 1][c] - Lvx[iV - 2][c])) * IDH_;
        mv3[k] = by * mv3[k] + bym1 * d;
        g += d + mv3[k];
        float sxy = (Lsxy[iS][c] + DT_ * muk * g) * mk;
        Lsxy[iS][c] = sxy;
        if (PUB) { cst(pubYY + c, syy); cst(pubXY + c, sxy); cst(pubXX + c, sxx); }
    }
}

__global__ void init_kernel(float* __restrict__ ws) {
    for (int i = blockIdx.x * 256 + threadIdx.x; i < WS_WORDS_; i += gridDim.x * 256)
        ws[i] = 0.0f;
}

__global__ __launch_bounds__(512)
void elastic_kernel(const float* __restrict__ lamb, const float* __restrict__ mu,
                    const float* __restrict__ buoy, const float* __restrict__ amps,
                    const int* __restrict__ src_loc, const int* __restrict__ rec_loc,
                    float* __restrict__ out, float* __restrict__ wsc)
{
    // LDS field tiles (relative rows; owned y=0..7):
    //   Lsyy/Lsxy: y -> y+8  (rows -8..15)
    //   Lsxx/Lvy/Lvx: y -> y+6 (rows -6..13)
    __shared__ float Lsyy[24][NX_], Lsxy[24][NX_], Lsxx[20][NX_], Lvy[20][NX_], Lvx[20][NX_];

    float* ws = wsc;
    const int tid  = threadIdx.x;
    const int lane = tid & 63;
    const int w    = tid >> 6;          // owned row 0..7 (one wave per row)
    const int bid  = blockIdx.x;
    const int s    = bid / NSTRIP_;
    const int j    = bid % NSTRIP_;
    const int r0   = j * 8;
    const int gy   = r0 + w;

    unsigned* flg = (unsigned*)(ws + FLG_OFF_);
    const int sbase = s * NSTRIP_;
    float* recp = ws + REC_OFF_ + (s * NREC_ + tid) * NT_;   // valid only if tid<96
    const float* ampsS = amps + s * NSRC_ * NT_;

    // ---- ghost-row assignments (fixed per wave; arithmetic only) ----
    // V1 ghosts: w0..7 -> {8,9,-6,-5,-4,-3,-2,-1}; deep 2nd ghost w2..5 -> {10,11,12,13}
    const int yG1 = (w < 2) ? (w + 8) : (w - 8);
    const bool hasG2 = (w >= 2 && w <= 5);
    const int yG2 = w + 8;
    // S1 ghosts: w0..7 -> {-4,-3,-2,-1,8,9,10,11}
    const int ySg = (w < 4) ? (w - 4) : (w + 4);
    // V2 ghosts {-2,-1,8,9} are w6,w7,w0,w1's yG1 (ms continuity held in regs)
    const bool hasV2g = (w < 2 || w > 5);

    const int gG1 = r0 + yG1, gG2 = r0 + yG2, gSg = r0 + ySg;
    const bool okG1 = (unsigned)gG1 < (unsigned)NY_;
    const bool okG2 = hasG2 && ((unsigned)gG2 < (unsigned)NY_);
    const bool okSg = (unsigned)gSg < (unsigned)NY_;

    // clamped row indices for pointer formation (deref only under ok*)
    const int cG1 = okG1 ? gG1 : 0, cG2 = okG2 ? gG2 : 0, cSg = okSg ? gSg : 0;

    // material row pointers (wave-uniform -> SGPR; loads are cached, L2-resident)
    const float* buO_p  = buoy + gy  * NX_;
    const float* laO_p  = lamb + gy  * NX_;
    const float* muO_p  = mu   + gy  * NX_;
    const float* buG1_p = buoy + cG1 * NX_;
    const float* buG2_p = buoy + cG2 * NX_;
    const float* laSg_p = lamb + cSg * NX_;
    const float* muSg_p = mu   + cSg * NX_;

    // per-row wave-uniform scalars
    const float byO  = pml_by(gy);
    const float byG1 = pml_by(gG1);
    const float byG2 = pml_by(gG2);
    const float bySg = pml_by(gSg);
    const float mrO  = (gy  >= 2 && gy  < NY_ - 2) ? 1.0f : 0.0f;
    const float mrG1 = (gG1 >= 2 && gG1 < NY_ - 2) ? 1.0f : 0.0f;
    const float mrG2 = (gG2 >= 2 && gG2 < NY_ - 2) ? 1.0f : 0.0f;
    const float mrSg = (gSg >= 2 && gSg < NY_ - 2) ? 1.0f : 0.0f;

    const double d0 = 3.0 * 1600.0 * log(1000.0) / (2.0 * 20.0 * 4.0);
    float bx2[2], bxm12[2], mkc2[2];
    #pragma unroll
    for (int e = 0; e < 2; ++e) {
        int c = (e == 0) ? lane : 256 + lane;   // groups k=0 and k=4
        double pxd = 0.0;
        if (c < 20)             { double u = (20.0 - c) / 20.0;           pxd = u * u; }
        else if (c >= NX_ - 20) { double u = (c - (NX_ - 1 - 20)) / 20.0; pxd = u * u; }
        bx2[e] = (float)exp(-d0 * pxd * 4.0e-4);
        bxm12[e] = bx2[e] - 1.0f;
        mkc2[e] = (c >= 2 && c < NX_ - 2) ? 1.0f : 0.0f;
    }

    const unsigned long long smO  = srcmask(src_loc, s, gy,  lane);
    const unsigned long long smG1 = srcmask(src_loc, s, gG1, lane);
    const unsigned long long smG2 = hasG2 ? srcmask(src_loc, s, gG2, lane) : 0ull;

    // per-thread receiver
    bool myrec = false; int rl = 0;
    if (tid < NREC_) {
        int ry = rec_loc[(s * NREC_ + tid) * 2 + 0];
        int rx = rec_loc[(s * NREC_ + tid) * 2 + 1];
        if ((ry >> 3) == j) { myrec = true; rl = ((ry & 7) + 6) * NX_ + rx; }
    }

    // zero LDS (fields start at 0)
    for (int i = tid; i < 24 * NX_; i += 512) { ((float*)Lsyy)[i] = 0.f; ((float*)Lsxy)[i] = 0.f; }
    for (int i = tid; i < 20 * NX_; i += 512) { ((float*)Lsxx)[i] = 0.f; ((float*)Lvy)[i] = 0.f; ((float*)Lvx)[i] = 0.f; }

    // ---- persistent register state: owned-row CPML only (x-packed) ----
    float msyyy[5] = {}, msxyy[5] = {}, msxyx[2] = {}, msxxx[2] = {};
    float mvyy[5] = {}, mvyx[2] = {}, mvxy[5] = {}, mvxx[2] = {};

    __syncthreads();

    for (int r = 0; r < NR_; ++r) {
        const int t0 = 2 * r;
        const int rb = r & 1, wb = rb ^ 1;   // ping-pong, flag-gated (race-free, rounds 1-4)

        // ============ single exchange point per 2 timesteps ============
        pollNbr(flg, sbase, j, (unsigned)r, tid);

        // ---- P0a: LDS halo imports (stress rows -8..-1/8..15; sxx +-6; deep v ghosts) ----
        if (tid < NX_) {
            const int c = tid;
            const float* rYY = SGp(ws, rb, 0, s);
            const float* rXY = SGp(ws, rb, 1, s);
            const float* rXX = SGp(ws, rb, 2, s);
            const float* rVY = VGp(ws, rb, 0, s);
            const float* rVX = VGp(ws, rb, 1, s);
            #pragma unroll
            for (int i = 0; i < 8; ++i) {
                Lsyy[i][c]      = gldf(rYY, r0 - 8 + i, c);
                Lsyy[16 + i][c] = gldf(rYY, r0 + 8 + i, c);
                Lsxy[i][c]      = gldf(rXY, r0 - 8 + i, c);
                Lsxy[16 + i][c] = gldf(rXY, r0 + 8 + i, c);
            }
            #pragma unroll
            for (int i = 0; i < 6; ++i) {
                Lsxx[i][c]      = gldf(rXX, r0 - 6 + i, c);
                Lsxx[14 + i][c] = gldf(rXX, r0 + 8 + i, c);
            }
            // deep v ghosts only (-6..-3 and 10..13); rows -2,-1,8,9 are locally exact
            #pragma unroll
            for (int i = 0; i < 4; ++i) {
                Lvy[i][c]      = gldf(rVY, r0 - 6 + i, c);
                Lvy[16 + i][c] = gldf(rVY, r0 + 10 + i, c);
                Lvx[i][c]      = gldf(rVX, r0 - 6 + i, c);
                Lvx[16 + i][c] = gldf(rVX, r0 + 10 + i, c);
            }
        }

        // ---- P0b: ghost CPML state -> registers (transient this round) ----
        float msG1a[5] = {}, msG1b[5] = {}, msG1c[2] = {}, msG1d[2] = {};
        float msG2a[5] = {}, msG2b[5] = {}, msG2c[2] = {}, msG2d[2] = {};
        float mvSg1[5] = {}, mvSg2[2] = {}, mvSg3[5] = {}, mvSg4[2] = {};
        if (okG1) {
            const float* a = MSfp(ws, rb, 0, s) + gG1 * NX_;
            const float* b = MSfp(ws, rb, 1, s) + gG1 * NX_;
            #pragma unroll
            for (int k = 0; k < 5; ++k) { msG1a[k] = cld(a + 64 * k + lane); msG1b[k] = cld(b + 64 * k + lane); }
            const float* p = MSpp(ws, rb, 0, s) + gG1 * PK_;
            const float* q = MSpp(ws, rb, 1, s) + gG1 * PK_;
            msG1c[0] = cld(p + lane); msG1c[1] = cld(p + 64 + lane);
            msG1d[0] = cld(q + lane); msG1d[1] = cld(q + 64 + lane);
        }
        if (okG2) {
            const float* a = MSfp(ws, rb, 0, s) + gG2 * NX_;
            const float* b = MSfp(ws, rb, 1, s) + gG2 * NX_;
            #pragma unroll
            for (int k = 0; k < 5; ++k) { msG2a[k] = cld(a + 64 * k + lane); msG2b[k] = cld(b + 64 * k + lane); }
            const float* p = MSpp(ws, rb, 0, s) + gG2 * PK_;
            const float* q = MSpp(ws, rb, 1, s) + gG2 * PK_;
            msG2c[0] = cld(p + lane); msG2c[1] = cld(p + 64 + lane);
            msG2d[0] = cld(q + lane); msG2d[1] = cld(q + 64 + lane);
        }
        if (okSg) {
            const float* a = MVfp(ws, rb, 0, s) + gSg * NX_;
            const float* b = MVfp(ws, rb, 1, s) + gSg * NX_;
            #pragma unroll
            for (int k = 0; k < 5; ++k) { mvSg1[k] = cld(a + 64 * k + lane); mvSg3[k] = cld(b + 64 * k + lane); }
            const float* p = MVpp(ws, rb, 0, s) + gSg * PK_;
            const float* q = MVpp(ws, rb, 1, s) + gSg * PK_;
            mvSg2[0] = cld(p + lane); mvSg2[1] = cld(p + 64 + lane);
            mvSg4[0] = cld(q + lane); mvSg4[1] = cld(q + 64 + lane);
        }
        __syncthreads();   // (A) halos + ghost state ready

        // ---- V1: v(t0) on rows -6..13 (owned + 1-2 ghosts per wave) ----
        vrowL<false>(lane, w, ampsS + t0, msyyy, msxyy, msxyx, msxxx,
                     byO, bx2, bxm12, buO_p, mrO, mkc2, smO,
                     Lsyy, Lsxy, Lsxx, Lvy, Lvx, nullptr, nullptr);
        if (okG1)
            vrowL<false>(lane, yG1, ampsS + t0, msG1a, msG1b, msG1c, msG1d,
                         byG1, bx2, bxm12, buG1_p, mrG1, mkc2, smG1,
                         Lsyy, Lsxy, Lsxx, Lvy, Lvx, nullptr, nullptr);
        if (okG2)
            vrowL<false>(lane, yG2, ampsS + t0, msG2a, msG2b, msG2c, msG2d,
                         byG2, bx2, bxm12, buG2_p, mrG2, mkc2, smG2,
                         Lsyy, Lsxy, Lsxx, Lvy, Lvx, nullptr, nullptr);
        __syncthreads();   // (B)
        if (myrec) recp[t0] = ((const float*)Lvy)[rl];

        // ---- S1: s(t0+1) on rows -4..11 (owned + 1 ghost per wave) ----
        srowL<false>(lane, w, mvyy, mvyx, mvxy, mvxx,
                     byO, bx2, bxm12, laO_p, muO_p, mrO, mkc2,
                     Lsyy, Lsxy, Lsxx, Lvy, Lvx, nullptr, nullptr, nullptr);
        if (okSg)
            srowL<false>(lane, ySg, mvSg1, mvSg2, mvSg3, mvSg4,
                         bySg, bx2, bxm12, laSg_p, muSg_p, mrSg, mkc2,
                         Lsyy, Lsxy, Lsxx, Lvy, Lvx, nullptr, nullptr, nullptr);
        __syncthreads();   // (C)

        // ---- V2: v(t0+1) on rows -2..9; publish owned v + owned ms ----
        {
            float* wVY = VGp(ws, wb, 0, s) + gy * NX_;
            float* wVX = VGp(ws, wb, 1, s) + gy * NX_;
            vrowL<true>(lane, w, ampsS + t0 + 1, msyyy, msxyy, msxyx, msxxx,
                        byO, bx2, bxm12, buO_p, mrO, mkc2, smO,
                        Lsyy, Lsxy, Lsxx, Lvy, Lvx, wVY, wVX);
            if (hasV2g && okG1)
                vrowL<false>(lane, yG1, ampsS + t0 + 1, msG1a, msG1b, msG1c, msG1d,
                             byG1, bx2, bxm12, buG1_p, mrG1, mkc2, smG1,
                             Lsyy, Lsxy, Lsxx, Lvy, Lvx, nullptr, nullptr);
            float* a = MSfp(ws, wb, 0, s) + gy * NX_;
            float* b = MSfp(ws, wb, 1, s) + gy * NX_;
            #pragma unroll
            for (int k = 0; k < 5; ++k) { cst(a + 64 * k + lane, msyyy[k]); cst(b + 64 * k + lane, msxyy[k]); }
            float* p = MSpp(ws, wb, 0, s) + gy * PK_;
            float* q = MSpp(ws, wb, 1, s) + gy * PK_;
            cst(p + lane, msxyx[0]); cst(p + 64 + lane, msxyx[1]);
            cst(q + lane, msxxx[0]); cst(q + 64 + lane, msxxx[1]);
        }
        __syncthreads();   // (D)
        if (myrec) recp[t0 + 1] = ((const float*)Lvy)[rl];

        // ---- S2: s(t0+2) on owned rows; publish owned s + owned mv ----
        {
            float* wYY = SGp(ws, wb, 0, s) + gy * NX_;
            float* wXY = SGp(ws, wb, 1, s) + gy * NX_;
            float* wXX = SGp(ws, wb, 2, s) + gy * NX_;
            srowL<true>(lane, w, mvyy, mvyx, mvxy, mvxx,
                        byO, bx2, bxm12, laO_p, muO_p, mrO, mkc2,
                        Lsyy, Lsxy, Lsxx, Lvy, Lvx, wYY, wXY, wXX);
            float* a = MVfp(ws, wb, 0, s) + gy * NX_;
            float* b = MVfp(ws, wb, 1, s) + gy * NX_;
            #pragma unroll
            for (int k = 0; k < 5; ++k) { cst(a + 64 * k + lane, mvyy[k]); cst(b + 64 * k + lane, mvxy[k]); }
            float* p = MVpp(ws, wb, 0, s) + gy * PK_;
            float* q = MVpp(ws, wb, 1, s) + gy * PK_;
            cst(p + lane, mvyx[0]); cst(p + 64 + lane, mvyx[1]);
            cst(q + lane, mvxx[0]); cst(q + 64 + lane, mvxx[1]);
        }
        __syncthreads();   // (E) — compiler drains each wave's vmcnt before s_barrier
        if (tid == 0) {
            asm volatile("s_waitcnt vmcnt(0)" ::: "memory");
            cstu(&flg[sbase + j], (unsigned)(r + 1));
        }
    }

    // ---------- final output: out[s][r][t] = 0.5*(rec[t] + rec[t+1]) ----------
    if (myrec) {
        float* op = out + (s * NREC_ + tid) * (NT_ - 1);
        for (int t = 0; t < NT_ - 1; ++t) op[t] = 0.5f * (recp[t] + recp[t + 1]);
    }
}

extern "C" void kernel_launch(void* const* d_in, const int* in_sizes, int n_in,
                              void* d_out, int out_size, void* d_ws, size_t ws_size,
                              hipStream_t stream)
{
    const float* lamb = (const float*)d_in[0];
    const float* mu   = (const float*)d_in[1];
    const float* buoy = (const float*)d_in[2];
    const float* amps = (const float*)d_in[3];
    const int*   src  = (const int*)d_in[4];
    const int*   recl = (const int*)d_in[5];
    float* out = (float*)d_out;
    float* ws  = (float*)d_ws;

    init_kernel<<<dim3(512), dim3(256), 0, stream>>>(ws);
    elastic_kernel<<<dim3(NBLK_), dim3(512), 0, stream>>>(lamb, mu, buoy, amps, src, recl, out, ws);
}

// Round 6
// 1550.226 us; speedup vs baseline: 1.7457x; 1.7457x over previous
//
#include <hip/hip_runtime.h>
#include <math.h>

constexpr int NY_ = 320, NX_ = 320, NT_ = 160, SHOTS_ = 2, NSRC_ = 8, NREC_ = 96;
constexpr float DT_  = 4.0e-4f;
constexpr float C1_  = 9.0f / 8.0f;
constexpr float C2_  = -1.0f / 24.0f;
constexpr float IDH_ = 0.25f;           // 1/DH, exact
constexpr int NP_     = NY_ * NX_;
constexpr int NSTRIP_ = 40;             // 8-row strips per shot
constexpr int NBLK_   = SHOTS_ * NSTRIP_;
// ws layout (float words): stress mirrors [buf2][field3: syy,sxy,sxx][shot2][NP],
// receiver traces, flags (monotonic round counters).
constexpr int REC_OFF_ = 12 * NP_;
constexpr int FLG_OFF_ = REC_OFF_ + SHOTS_ * NREC_ * NT_;
constexpr int WS_WORDS_ = FLG_OFF_ + 128;

// ---- coherent (IF-backed) access: relaxed agent-scope atomics ----
__device__ __forceinline__ float cld(const float* p) {
    return __hip_atomic_load(p, __ATOMIC_RELAXED, __HIP_MEMORY_SCOPE_AGENT);
}
__device__ __forceinline__ void cst(float* p, float v) {
    __hip_atomic_store(p, v, __ATOMIC_RELAXED, __HIP_MEMORY_SCOPE_AGENT);
}
__device__ __forceinline__ unsigned cldu(const unsigned* p) {
    return __hip_atomic_load(p, __ATOMIC_RELAXED, __HIP_MEMORY_SCOPE_AGENT);
}
__device__ __forceinline__ void cstu(unsigned* p, unsigned v) {
    __hip_atomic_store(p, v, __ATOMIC_RELAXED, __HIP_MEMORY_SCOPE_AGENT);
}

// guarded halo import load: out-of-grid rows read 0 (== masked border equivalence)
__device__ __forceinline__ float gldf(const float* p, int y, int c) {
    return ((unsigned)y < (unsigned)NY_) ? cld(p + y * NX_ + c) : 0.0f;
}
// guarded LDS x-tap: out-of-grid cols read 0
__device__ __forceinline__ float ltap(const float (*A)[NX_], int ly, int c) {
    return ((unsigned)c < (unsigned)NX_) ? A[ly][c] : 0.0f;
}
// register x-tap via wave shuffle (cells are 64-col interleaved, 5 groups/lane)
__device__ __forceinline__ float shtap(float cur, float adj, int lane, int dx) {
    int idx = (lane + dx) & 63;
    float a = __shfl(cur, idx, 64);
    float b = __shfl(adj, idx, 64);
    return ((unsigned)(lane + dx) < 64u) ? a : b;
}

__device__ __forceinline__ float pml_by(int gy) {
    const double d0 = 3.0 * 1600.0 * log(1000.0) / (2.0 * 20.0 * 4.0);
    double py = 0.0;
    if (gy < 20)             { double u = (20.0 - gy) / 20.0;           py = u * u; }
    else if (gy >= NY_ - 20) { double u = (gy - (NY_ - 1 - 20)) / 20.0; py = u * u; }
    return (float)exp(-d0 * py * 4.0e-4);
}

__device__ __forceinline__ unsigned long long srcmask(const int* __restrict__ src_loc,
                                                      int s, int gy, int lane) {
    unsigned long long sm = 0ull;
    if ((unsigned)gy < (unsigned)NY_) {
        for (int js = 0; js < NSRC_; ++js) {
            int sy = src_loc[(s * NSRC_ + js) * 2 + 0];
            int sx = src_loc[(s * NSRC_ + js) * 2 + 1];
            if (sy == gy && (sx & 63) == lane) sm |= 1ull << (8 * (sx >> 6) + js);
        }
    }
    return sm;
}

// x-CPML static sparsity: groups k=1,2,3 (cols 64..255) have bx=1 -> x memory vars
// stay exactly 0 forever -> packed [2] arrays hold only k=0,k=4. Bit-exact.

// ---- one row's velocity + CPML update (self stress from LDS; sxx from regs) ----
__device__ __forceinline__ void vrow(
    int lane, const float* __restrict__ ampsT,
    float (&VY)[5], float (&VX)[5],
    float (&MS1)[5], float (&MS2)[5], float (&MS3)[2], float (&MS4)[2], // msyyy,msxyy,msxyx,msxxx
    const float (&SXX)[5],
    int lyS, int lxS, int lv,
    float by, const float (&bx2)[2], const float (&bxm12)[2],
    const float* __restrict__ buRow, float mr, const float (&mkc2)[2],
    unsigned long long sm,
    const float (*Lsyy)[NX_], const float (*Lsxy)[NX_],
    float (*Lvy)[NX_], float (*Lvx)[NX_])
{
    const float bym1 = by - 1.0f;
    #pragma unroll
    for (int k = 0; k < 5; ++k) {
        const int c = 64 * k + lane;
        const bool px = (k == 0 || k == 4);
        const int xk = (k == 0) ? 0 : 1;
        const float mk = mr * (px ? mkc2[xk] : 1.0f);
        const float buk = buRow[c];
        // D-_y(syy)
        float d = (C1_ * (Lsyy[lyS][c] - Lsyy[lyS - 1][c])
                 + C2_ * (Lsyy[lyS + 1][c] - Lsyy[lyS - 2][c])) * IDH_;
        MS1[k] = by * MS1[k] + bym1 * d;
        float ay = d + MS1[k];
        // D+_x(sxy)
        d = (C1_ * (ltap(Lsxy, lxS, c + 1) - Lsxy[lxS][c])
           + C2_ * (ltap(Lsxy, lxS, c + 2) - ltap(Lsxy, lxS, c - 1))) * IDH_;
        if (px) { MS3[xk] = bx2[xk] * MS3[xk] + bxm12[xk] * d; ay += d + MS3[xk]; }
        else    { ay += d; }
        VY[k] = VY[k] + DT_ * buk * ay;
        unsigned m = (unsigned)(sm >> (8 * k)) & 0xFFu;
        if (m) {
            for (int js = 0; js < NSRC_; ++js)
                if (m & (1u << js)) VY[k] += DT_ * ampsT[js * NT_] * buk;
        }
        VY[k] *= mk;
        // D-_x(sxx) via register shuffles
        const float sxxp = (k < 4) ? SXX[k + 1] : 0.0f;
        const float sxxm = (k > 0) ? SXX[k - 1] : 0.0f;
        d = (C1_ * (SXX[k] - shtap(SXX[k], sxxm, lane, -1))
           + C2_ * (shtap(SXX[k], sxxp, lane, 1) - shtap(SXX[k], sxxm, lane, -2))) * IDH_;
        float ax;
        if (px) { MS4[xk] = bx2[xk] * MS4[xk] + bxm12[xk] * d; ax = d + MS4[xk]; }
        else    { ax = d; }
        // D+_y(sxy)
        d = (C1_ * (Lsxy[lxS + 1][c] - Lsxy[lxS][c])
           + C2_ * (Lsxy[lxS + 2][c] - Lsxy[lxS - 1][c])) * IDH_;
        MS2[k] = by * MS2[k] + bym1 * d;
        ax += d + MS2[k];
        VX[k] = (VX[k] + DT_ * buk * ax) * mk;
        Lvy[lv][c] = VY[k]; Lvx[lv][c] = VX[k];
    }
}

__global__ void init_kernel(float* __restrict__ ws) {
    for (int i = blockIdx.x * 256 + threadIdx.x; i < WS_WORDS_; i += gridDim.x * 256)
        ws[i] = 0.0f;
}

__global__ __launch_bounds__(512)
void elastic_kernel(const float* __restrict__ lamb, const float* __restrict__ mu,
                    const float* __restrict__ buoy, const float* __restrict__ amps,
                    const int* __restrict__ src_loc, const int* __restrict__ rec_loc,
                    float* __restrict__ out, float* __restrict__ ws)
{
    // LDS row maps: Lvy/Lvx: y -> y+2 (rows -2..9)
    //               Lsyy:    y -> y+4 (rows -4..10)
    //               Lsxy:    y -> y+3 (rows -3..11)
    __shared__ float Lvy[12][NX_], Lvx[12][NX_], Lsyy[15][NX_], Lsxy[15][NX_];

    const int tid  = threadIdx.x;
    const int lane = tid & 63;
    const int w    = tid >> 6;          // owned row 0..7 (one wave per row)
    const int bid  = blockIdx.x;
    const int s    = bid / NSTRIP_;
    const int j    = bid % NSTRIP_;
    const int r0   = j * 8;
    const int gy   = r0 + w;

    unsigned* flg = (unsigned*)(ws + FLG_OFF_);
    const int sbase = s * NSTRIP_;
    float* recp = ws + REC_OFF_ + (s * NREC_ + tid) * NT_;   // valid only if tid<96
    const float* ampsS = amps + s * NSRC_ * NT_;

    // ghost-row assignment: waves 0,1 evolve rows -2,-1; waves 6,7 rows 8,9
    const bool isE = (w < 2) || (w >= 6);
    const bool midw = !isE;
    const int  yE  = (w < 2) ? (w - 2) : (w + 2);
    const int  gyE = r0 + yE;
    const bool hasE = isE && ((unsigned)gyE < (unsigned)NY_);
    const int lySE = yE + 4, lxSE = yE + 3, lvE = yE + 2;
    const int cEr = hasE ? gyE : 0;

    // material row base pointers (wave-uniform -> SGPR; regular cached loads)
    const float* buO_p = buoy + gy * NX_;
    const float* laO_p = lamb + gy * NX_;
    const float* muO_p = mu   + gy * NX_;
    const float* buE_p = buoy + cEr * NX_;

    // per-row wave-uniform scalars
    const float by   = pml_by(gy);
    const float bym1 = by - 1.0f;
    const float byE  = pml_by(gyE);
    const float mrO  = (gy  >= 2 && gy  < NY_ - 2) ? 1.0f : 0.0f;
    const float mrE  = (gyE >= 2 && gyE < NY_ - 2) ? 1.0f : 0.0f;

    const double d0 = 3.0 * 1600.0 * log(1000.0) / (2.0 * 20.0 * 4.0);
    float bx2[2], bxm12[2], mkc2[2];
    #pragma unroll
    for (int e = 0; e < 2; ++e) {
        int c = (e == 0) ? lane : 256 + lane;   // groups k=0 and k=4
        double pxd = 0.0;
        if (c < 20)             { double u = (20.0 - c) / 20.0;           pxd = u * u; }
        else if (c >= NX_ - 20) { double u = (c - (NX_ - 1 - 20)) / 20.0; pxd = u * u; }
        bx2[e] = (float)exp(-d0 * pxd * 4.0e-4);
        bxm12[e] = bx2[e] - 1.0f;
        mkc2[e] = (c >= 2 && c < NX_ - 2) ? 1.0f : 0.0f;
    }

    const unsigned long long smO = srcmask(src_loc, s, gy, lane);
    const unsigned long long smE = hasE ? srcmask(src_loc, s, gyE, lane) : 0ull;

    // per-thread receiver (tid<96 handles receiver tid of this shot)
    bool myrec = false; int rl = 0;
    if (tid < NREC_) {
        int ry = rec_loc[(s * NREC_ + tid) * 2 + 0];
        int rx = rec_loc[(s * NREC_ + tid) * 2 + 1];
        if ((ry >> 3) == j) { myrec = true; rl = ((ry & 7) + 2) * NX_ + rx; }
    }

    // zero LDS (fields start at 0)
    for (int i = tid; i < 15 * NX_; i += 512) {
        if (i < 12 * NX_) { ((float*)Lvy)[i] = 0.f; ((float*)Lvx)[i] = 0.f; }
        ((float*)Lsyy)[i] = 0.f; ((float*)Lsxy)[i] = 0.f;
    }

    // ---- register state (x-CPML packed) ----
    float vy[5] = {}, vx[5] = {}, syy[5] = {}, sxy[5] = {}, sxx[5] = {};
    float msyyy[5] = {}, msxyy[5] = {}, msxyx[2] = {}, msxxx[2] = {};
    float mvyy[5] = {}, mvyx[2] = {}, mvxy[5] = {}, mvxx[2] = {};
    float vyE[5] = {}, vxE[5] = {};
    float msyyyE[5] = {}, msxyyE[5] = {}, msxyxE[2] = {}, msxxxE[2] = {};

    __syncthreads();

    for (int t = 0; t < NT_; ++t) {
        const int rb = t & 1, wb = rb ^ 1;   // ping-pong stress mirrors, flag-gated
        const float* rSyy = ws + ((rb * 3 + 0) * SHOTS_ + s) * NP_;
        const float* rSxy = ws + ((rb * 3 + 1) * SHOTS_ + s) * NP_;
        const float* rSxx = ws + ((rb * 3 + 2) * SHOTS_ + s) * NP_;
        float* wSyy = ws + ((wb * 3 + 0) * SHOTS_ + s) * NP_;
        float* wSxy = ws + ((wb * 3 + 1) * SHOTS_ + s) * NP_;
        float* wSxx = ws + ((wb * 3 + 2) * SHOTS_ + s) * NP_;

        // ======== pre-A: poll (wave 0) OVERLAPPED with interior velocity ========
        // Interior rows 2..5 tap only strip-local stress (syy rows 0..7, sxy 1..7)
        // written to LDS last round -> no dependence on the neighbor flag.
        if (w == 0) {
            for (;;) {
                bool ok = true;
                if (lane == 0 && j > 0)                ok = cldu(&flg[sbase + j - 1]) >= (unsigned)t;
                else if (lane == 1 && j < NSTRIP_ - 1) ok = cldu(&flg[sbase + j + 1]) >= (unsigned)t;
                if (__all(ok)) break;
                __builtin_amdgcn_s_sleep(1);
            }
        } else if (midw) {
            vrow(lane, ampsS + t, vy, vx, msyyy, msxyy, msxyx, msxxx, sxx,
                 w + 4, w + 3, w + 2, by, bx2, bxm12, buO_p, mrO, mkc2, smO,
                 Lsyy, Lsxy, Lvy, Lvx);
        }
        __syncthreads();   // (A) poll complete + interior V done
        asm volatile("" ::: "memory");

        // ======== import stress halos (14 rows) + ghost sxx into registers ========
        if (tid < NX_) {
            int c = tid;
            float a0 = gldf(rSyy, r0 - 4, c), a1 = gldf(rSyy, r0 - 3, c);
            float a2 = gldf(rSyy, r0 - 2, c), a3 = gldf(rSyy, r0 - 1, c);
            float a4 = gldf(rSyy, r0 + 8, c), a5 = gldf(rSyy, r0 + 9, c), a6 = gldf(rSyy, r0 + 10, c);
            float b0 = gldf(rSxy, r0 - 3, c), b1 = gldf(rSxy, r0 - 2, c), b2 = gldf(rSxy, r0 - 1, c);
            float b3 = gldf(rSxy, r0 + 8, c), b4 = gldf(rSxy, r0 + 9, c);
            float b5 = gldf(rSxy, r0 + 10, c), b6 = gldf(rSxy, r0 + 11, c);
            Lsyy[0][c] = a0; Lsyy[1][c] = a1; Lsyy[2][c] = a2; Lsyy[3][c] = a3;
            Lsyy[12][c] = a4; Lsyy[13][c] = a5; Lsyy[14][c] = a6;
            Lsxy[0][c] = b0; Lsxy[1][c] = b1; Lsxy[2][c] = b2;
            Lsxy[11][c] = b3; Lsxy[12][c] = b4; Lsxy[13][c] = b5; Lsxy[14][c] = b6;
        }
        float sxxE[5] = {};
        if (hasE) {
            #pragma unroll
            for (int k = 0; k < 5; ++k) sxxE[k] = cld(rSxx + gyE * NX_ + 64 * k + lane);
        }
        __syncthreads();   // (B) halos ready

        // ======== edge velocity: waves 0,1,6,7 -> owned rows 0,1,6,7 + ghosts ========
        if (isE) {
            vrow(lane, ampsS + t, vy, vx, msyyy, msxyy, msxyx, msxxx, sxx,
                 w + 4, w + 3, w + 2, by, bx2, bxm12, buO_p, mrO, mkc2, smO,
                 Lsyy, Lsxy, Lvy, Lvx);
            if (hasE)
                vrow(lane, ampsS + t, vyE, vxE, msyyyE, msxyyE, msxyxE, msxxxE, sxxE,
                     lySE, lxSE, lvE, byE, bx2, bxm12, buE_p, mrE, mkc2, smE,
                     Lsyy, Lsxy, Lvy, Lvx);
        }
        __syncthreads();   // (C) all velocity rows -2..9 current

        // record receivers (strip-local)
        if (myrec) recp[t] = ((const float*)Lvy)[rl];

        // ======== stress: all waves, owned rows; inline publish from registers ========
        {
            const int lv = w + 2;
            #pragma unroll
            for (int k = 0; k < 5; ++k) {
                const int c = 64 * k + lane;
                const bool px = (k == 0 || k == 4);
                const int xk = (k == 0) ? 0 : 1;
                const float mk = mrO * (px ? mkc2[xk] : 1.0f);
                const float lak = laO_p[c];
                const float muk = muO_p[c];
                float d, e1, e2, g;
                // D+_y(vy)
                d = (C1_ * (Lvy[lv + 1][c] - vy[k]) + C2_ * (Lvy[lv + 2][c] - Lvy[lv - 1][c])) * IDH_;
                mvyy[k] = by * mvyy[k] + bym1 * d;
                e1 = d + mvyy[k];
                // D-_x(vx)
                d = (C1_ * (vx[k] - ltap(Lvx, lv, c - 1))
                   + C2_ * (ltap(Lvx, lv, c + 1) - ltap(Lvx, lv, c - 2))) * IDH_;
                if (px) { mvxx[xk] = bx2[xk] * mvxx[xk] + bxm12[xk] * d; e2 = d + mvxx[xk]; }
                else    { e2 = d; }
                const float l2m = lak + 2.0f * muk;
                syy[k] = (syy[k] + DT_ * (l2m * e1 + lak * e2)) * mk;
                sxx[k] = (sxx[k] + DT_ * (l2m * e2 + lak * e1)) * mk;
                // D+_x(vy)
                d = (C1_ * (ltap(Lvy, lv, c + 1) - vy[k])
                   + C2_ * (ltap(Lvy, lv, c + 2) - ltap(Lvy, lv, c - 1))) * IDH_;
                if (px) { mvyx[xk] = bx2[xk] * mvyx[xk] + bxm12[xk] * d; g = d + mvyx[xk]; }
                else    { g = d; }
                // D-_y(vx)
                d = (C1_ * (vx[k] - Lvx[lv - 1][c]) + C2_ * (Lvx[lv + 1][c] - Lvx[lv - 2][c])) * IDH_;
                mvxy[k] = by * mvxy[k] + bym1 * d;
                g = g + d + mvxy[k];
                sxy[k] = (sxy[k] + DT_ * muk * g) * mk;
                Lsyy[w + 4][c] = syy[k];
                Lsxy[w + 3][c] = sxy[k];
                // publish exactly the rows neighbors import:
                // syy rows {0..7}\{3}, sxy {0..7}\{4}, sxx {0,1,6,7}
                if (w != 3) cst(&wSyy[gy * NX_ + c], syy[k]);
                if (w != 4) cst(&wSxy[gy * NX_ + c], sxy[k]);
                if (isE)    cst(&wSxx[gy * NX_ + c], sxx[k]);
            }
        }
        __syncthreads();   // (D) — compiler drains each wave's vmcnt before s_barrier
        if (tid == 0) {
            asm volatile("s_waitcnt vmcnt(0)" ::: "memory");
            cstu(&flg[sbase + j], (unsigned)(t + 1));
        }
    }

    // ---------- final output: out[s][r][t] = 0.5*(rec[t] + rec[t+1]) ----------
    if (myrec) {
        float* op = out + (s * NREC_ + tid) * (NT_ - 1);
        for (int t = 0; t < NT_ - 1; ++t) op[t] = 0.5f * (recp[t] + recp[t + 1]);
    }
}

extern "C" void kernel_launch(void* const* d_in, const int* in_sizes, int n_in,
                              void* d_out, int out_size, void* d_ws, size_t ws_size,
                              hipStream_t stream)
{
    const float* lamb = (const float*)d_in[0];
    const float* mu   = (const float*)d_in[1];
    const float* buoy = (const float*)d_in[2];
    const float* amps = (const float*)d_in[3];
    const int*   src  = (const int*)d_in[4];
    const int*   recl = (const int*)d_in[5];
    float* out = (float*)d_out;
    float* ws  = (float*)d_ws;

    init_kernel<<<dim3(512), dim3(256), 0, stream>>>(ws);
    elastic_kernel<<<dim3(NBLK_), dim3(512), 0, stream>>>(lamb, mu, buoy, amps, src, recl, out, ws);
}

// Round 7
// 1344.671 us; speedup vs baseline: 2.0126x; 1.1529x over previous
//
#include <hip/hip_runtime.h>
#include <math.h>

constexpr int NY_ = 320, NX_ = 320, NT_ = 160, SHOTS_ = 2, NSRC_ = 8, NREC_ = 96;
constexpr float DT_  = 4.0e-4f;
constexpr float C1_  = 9.0f / 8.0f;
constexpr float C2_  = -1.0f / 24.0f;
constexpr float IDH_ = 0.25f;           // 1/DH, exact
constexpr int NP_     = NY_ * NX_;
constexpr int NSTRIP_ = 40;             // 8-row strips per shot
constexpr int NBLK_   = SHOTS_ * NSTRIP_;
// ws layout (float words): stress mirrors [buf2][field3: syy,sxy,sxx][shot2][NP],
// receiver traces, flags (monotonic round counters).
constexpr int REC_OFF_ = 12 * NP_;
constexpr int FLG_OFF_ = REC_OFF_ + SHOTS_ * NREC_ * NT_;
constexpr int WS_WORDS_ = FLG_OFF_ + 128;

// ---- coherent (IF-backed) access: relaxed agent-scope atomics ----
__device__ __forceinline__ float cld(const float* p) {
    return __hip_atomic_load(p, __ATOMIC_RELAXED, __HIP_MEMORY_SCOPE_AGENT);
}
__device__ __forceinline__ void cst(float* p, float v) {
    __hip_atomic_store(p, v, __ATOMIC_RELAXED, __HIP_MEMORY_SCOPE_AGENT);
}
__device__ __forceinline__ unsigned cldu(const unsigned* p) {
    return __hip_atomic_load(p, __ATOMIC_RELAXED, __HIP_MEMORY_SCOPE_AGENT);
}
__device__ __forceinline__ void cstu(unsigned* p, unsigned v) {
    __hip_atomic_store(p, v, __ATOMIC_RELAXED, __HIP_MEMORY_SCOPE_AGENT);
}

// guarded halo import load: out-of-grid rows read 0 (== masked border equivalence)
__device__ __forceinline__ float gldf(const float* p, int y, int c) {
    return ((unsigned)y < (unsigned)NY_) ? cld(p + y * NX_ + c) : 0.0f;
}
// guarded LDS x-tap: out-of-grid cols read 0
__device__ __forceinline__ float ltap(const float (*A)[NX_], int ly, int c) {
    return ((unsigned)c < (unsigned)NX_) ? A[ly][c] : 0.0f;
}
// register x-tap via wave shuffle (cells are 64-col interleaved, 5 groups/lane)
__device__ __forceinline__ float shtap(float cur, float adj, int lane, int dx) {
    int idx = (lane + dx) & 63;
    float a = __shfl(cur, idx, 64);
    float b = __shfl(adj, idx, 64);
    return ((unsigned)(lane + dx) < 64u) ? a : b;
}

__device__ __forceinline__ float pml_by(int gy) {
    const double d0 = 3.0 * 1600.0 * log(1000.0) / (2.0 * 20.0 * 4.0);
    double py = 0.0;
    if (gy < 20)             { double u = (20.0 - gy) / 20.0;           py = u * u; }
    else if (gy >= NY_ - 20) { double u = (gy - (NY_ - 1 - 20)) / 20.0; py = u * u; }
    return (float)exp(-d0 * py * 4.0e-4);
}

__device__ __forceinline__ unsigned long long srcmask(const int* __restrict__ src_loc,
                                                      int s, int gy, int lane) {
    unsigned long long sm = 0ull;
    if ((unsigned)gy < (unsigned)NY_) {
        for (int js = 0; js < NSRC_; ++js) {
            int sy = src_loc[(s * NSRC_ + js) * 2 + 0];
            int sx = src_loc[(s * NSRC_ + js) * 2 + 1];
            if (sy == gy && (sx & 63) == lane) sm |= 1ull << (8 * (sx >> 6) + js);
        }
    }
    return sm;
}

// x-CPML static sparsity: groups k=1,2,3 (cols 64..255) have bx=1 -> x memory vars
// stay exactly 0 forever -> packed [2] arrays hold only k=0,k=4. Bit-exact.

// ---- one row's velocity + CPML update (self stress from LDS; sxx from regs) ----
__device__ __forceinline__ void vrow(
    int lane, const float* __restrict__ ampsT,
    float (&VY)[5], float (&VX)[5],
    float (&MS1)[5], float (&MS2)[5], float (&MS3)[2], float (&MS4)[2], // msyyy,msxyy,msxyx,msxxx
    const float (&SXX)[5],
    int lyS, int lxS, int lv,
    float by, const float (&bx2)[2], const float (&bxm12)[2],
    const float* __restrict__ buRow, float mr, const float (&mkc2)[2],
    unsigned long long sm,
    const float (*Lsyy)[NX_], const float (*Lsxy)[NX_],
    float (*Lvy)[NX_], float (*Lvx)[NX_])
{
    const float bym1 = by - 1.0f;
    #pragma unroll
    for (int k = 0; k < 5; ++k) {
        const int c = 64 * k + lane;
        const bool px = (k == 0 || k == 4);
        const int xk = (k == 0) ? 0 : 1;
        const float mk = mr * (px ? mkc2[xk] : 1.0f);
        const float buk = buRow[c];
        // D-_y(syy)
        float d = (C1_ * (Lsyy[lyS][c] - Lsyy[lyS - 1][c])
                 + C2_ * (Lsyy[lyS + 1][c] - Lsyy[lyS - 2][c])) * IDH_;
        MS1[k] = by * MS1[k] + bym1 * d;
        float ay = d + MS1[k];
        // D+_x(sxy)
        d = (C1_ * (ltap(Lsxy, lxS, c + 1) - Lsxy[lxS][c])
           + C2_ * (ltap(Lsxy, lxS, c + 2) - ltap(Lsxy, lxS, c - 1))) * IDH_;
        if (px) { MS3[xk] = bx2[xk] * MS3[xk] + bxm12[xk] * d; ay += d + MS3[xk]; }
        else    { ay += d; }
        VY[k] = VY[k] + DT_ * buk * ay;
        unsigned m = (unsigned)(sm >> (8 * k)) & 0xFFu;
        if (m) {
            for (int js = 0; js < NSRC_; ++js)
                if (m & (1u << js)) VY[k] += DT_ * ampsT[js * NT_] * buk;
        }
        VY[k] *= mk;
        // D-_x(sxx) via register shuffles
        const float sxxp = (k < 4) ? SXX[k + 1] : 0.0f;
        const float sxxm = (k > 0) ? SXX[k - 1] : 0.0f;
        d = (C1_ * (SXX[k] - shtap(SXX[k], sxxm, lane, -1))
           + C2_ * (shtap(SXX[k], sxxp, lane, 1) - shtap(SXX[k], sxxm, lane, -2))) * IDH_;
        float ax;
        if (px) { MS4[xk] = bx2[xk] * MS4[xk] + bxm12[xk] * d; ax = d + MS4[xk]; }
        else    { ax = d; }
        // D+_y(sxy)
        d = (C1_ * (Lsxy[lxS + 1][c] - Lsxy[lxS][c])
           + C2_ * (Lsxy[lxS + 2][c] - Lsxy[lxS - 1][c])) * IDH_;
        MS2[k] = by * MS2[k] + bym1 * d;
        ax += d + MS2[k];
        VX[k] = (VX[k] + DT_ * buk * ax) * mk;
        Lvy[lv][c] = VY[k]; Lvx[lv][c] = VX[k];
    }
}

__global__ void init_kernel(float* __restrict__ ws) {
    for (int i = blockIdx.x * 256 + threadIdx.x; i < WS_WORDS_; i += gridDim.x * 256)
        ws[i] = 0.0f;
}

__global__ __launch_bounds__(512)
void elastic_kernel(const float* __restrict__ lamb, const float* __restrict__ mu,
                    const float* __restrict__ buoy, const float* __restrict__ amps,
                    const int* __restrict__ src_loc, const int* __restrict__ rec_loc,
                    float* __restrict__ out, float* __restrict__ ws)
{
    // LDS row maps: Lvy/Lvx: y -> y+2 (rows -2..9)
    //               Lsyy:    y -> y+4 (rows -4..10)
    //               Lsxy:    y -> y+3 (rows -3..11)
    __shared__ float Lvy[12][NX_], Lvx[12][NX_], Lsyy[15][NX_], Lsxy[15][NX_];

    const int tid  = threadIdx.x;
    const int lane = tid & 63;
    const int w    = tid >> 6;          // owned row 0..7 (one wave per row)
    const int bid  = blockIdx.x;
    const int s    = bid / NSTRIP_;
    const int j    = bid % NSTRIP_;
    const int r0   = j * 8;
    const int gy   = r0 + w;

    unsigned* flg = (unsigned*)(ws + FLG_OFF_);
    const int sbase = s * NSTRIP_;
    float* recp = ws + REC_OFF_ + (s * NREC_ + tid) * NT_;   // valid only if tid<96
    const float* ampsS = amps + s * NSRC_ * NT_;

    // role split: edge waves {0,1,6,7} = halo importers (their owned rows need the
    // imports anyway); interior waves {2..5} = flag-free owned compute + ghost rows.
    const bool isE = (w < 2) || (w >= 6);
    const bool top = (w < 2);
    // ghost rows (interior waves): w2..5 -> y {-2,-1,8,9}
    const int  yE  = (w < 4) ? (w - 4) : (w + 4);
    const int  gyE = r0 + yE;
    const bool hasG = (!isE) && ((unsigned)gyE < (unsigned)NY_);
    const int lySE = yE + 4, lxSE = yE + 3, lvE = yE + 2;
    const int cEr = hasG ? gyE : 0;

    // material row base pointers (wave-uniform -> SGPR; regular cached loads)
    const float* buO_p = buoy + gy * NX_;
    const float* laO_p = lamb + gy * NX_;
    const float* muO_p = mu   + gy * NX_;
    const float* buE_p = buoy + cEr * NX_;

    // per-row wave-uniform scalars
    const float by   = pml_by(gy);
    const float bym1 = by - 1.0f;
    const float byE  = pml_by(gyE);
    const float mrO  = (gy  >= 2 && gy  < NY_ - 2) ? 1.0f : 0.0f;
    const float mrE  = (gyE >= 2 && gyE < NY_ - 2) ? 1.0f : 0.0f;

    const double d0 = 3.0 * 1600.0 * log(1000.0) / (2.0 * 20.0 * 4.0);
    float bx2[2], bxm12[2], mkc2[2];
    #pragma unroll
    for (int e = 0; e < 2; ++e) {
        int c = (e == 0) ? lane : 256 + lane;   // groups k=0 and k=4
        double pxd = 0.0;
        if (c < 20)             { double u = (20.0 - c) / 20.0;           pxd = u * u; }
        else if (c >= NX_ - 20) { double u = (c - (NX_ - 1 - 20)) / 20.0; pxd = u * u; }
        bx2[e] = (float)exp(-d0 * pxd * 4.0e-4);
        bxm12[e] = bx2[e] - 1.0f;
        mkc2[e] = (c >= 2 && c < NX_ - 2) ? 1.0f : 0.0f;
    }

    const unsigned long long smO = srcmask(src_loc, s, gy, lane);
    const unsigned long long smE = hasG ? srcmask(src_loc, s, gyE, lane) : 0ull;

    // per-thread receiver (tid<96 handles receiver tid of this shot)
    bool myrec = false; int rl = 0;
    if (tid < NREC_) {
        int ry = rec_loc[(s * NREC_ + tid) * 2 + 0];
        int rx = rec_loc[(s * NREC_ + tid) * 2 + 1];
        if ((ry >> 3) == j) { myrec = true; rl = ((ry & 7) + 2) * NX_ + rx; }
    }

    // zero LDS (fields start at 0)
    for (int i = tid; i < 15 * NX_; i += 512) {
        if (i < 12 * NX_) { ((float*)Lvy)[i] = 0.f; ((float*)Lvx)[i] = 0.f; }
        ((float*)Lsyy)[i] = 0.f; ((float*)Lsxy)[i] = 0.f;
    }

    // ---- register state (x-CPML packed); ghost state lives in interior waves ----
    float vy[5] = {}, vx[5] = {}, syy[5] = {}, sxy[5] = {}, sxx[5] = {};
    float msyyy[5] = {}, msxyy[5] = {}, msxyx[2] = {}, msxxx[2] = {};
    float mvyy[5] = {}, mvyx[2] = {}, mvxy[5] = {}, mvxx[2] = {};
    float vyE[5] = {}, vxE[5] = {};
    float msyyyE[5] = {}, msxyyE[5] = {}, msxyxE[2] = {}, msxxxE[2] = {};

    __syncthreads();

    for (int t = 0; t < NT_; ++t) {
        const int rb = t & 1, wb = rb ^ 1;   // ping-pong stress mirrors, flag-gated
        const float* rSyy = ws + ((rb * 3 + 0) * SHOTS_ + s) * NP_;
        const float* rSxy = ws + ((rb * 3 + 1) * SHOTS_ + s) * NP_;
        const float* rSxx = ws + ((rb * 3 + 2) * SHOTS_ + s) * NP_;
        float* wSyy = ws + ((wb * 3 + 0) * SHOTS_ + s) * NP_;
        float* wSxy = ws + ((wb * 3 + 1) * SHOTS_ + s) * NP_;
        float* wSxx = ws + ((wb * 3 + 2) * SHOTS_ + s) * NP_;

        // ==== phase 1: {edge: poll side flag + import side halo (7 rows)} ||
        //              {interior: owned velocity (flag-free) + ghost sxx load} ====
        float sxxE[5] = {};
        if (isE) {
            if (top ? (j > 0) : (j < NSTRIP_ - 1)) {
                const unsigned* fad = top ? &flg[sbase + j - 1] : &flg[sbase + j + 1];
                while (cldu(fad) < (unsigned)t) __builtin_amdgcn_s_sleep(1);
            }
            const int tp = tid & 127;   // 0..127 within the side pair
            #pragma unroll
            for (int i = 0; i < 3; ++i) {
                const int c = tp + i * 128;
                if (c < NX_) {
                    if (top) {
                        float a0 = gldf(rSyy, r0 - 4, c), a1 = gldf(rSyy, r0 - 3, c);
                        float a2 = gldf(rSyy, r0 - 2, c), a3 = gldf(rSyy, r0 - 1, c);
                        float b0 = gldf(rSxy, r0 - 3, c), b1 = gldf(rSxy, r0 - 2, c);
                        float b2 = gldf(rSxy, r0 - 1, c);
                        Lsyy[0][c] = a0; Lsyy[1][c] = a1; Lsyy[2][c] = a2; Lsyy[3][c] = a3;
                        Lsxy[0][c] = b0; Lsxy[1][c] = b1; Lsxy[2][c] = b2;
                    } else {
                        float a0 = gldf(rSyy, r0 + 8, c), a1 = gldf(rSyy, r0 + 9, c);
                        float a2 = gldf(rSyy, r0 + 10, c);
                        float b0 = gldf(rSxy, r0 + 8, c), b1 = gldf(rSxy, r0 + 9, c);
                        float b2 = gldf(rSxy, r0 + 10, c), b3 = gldf(rSxy, r0 + 11, c);
                        Lsyy[12][c] = a0; Lsyy[13][c] = a1; Lsyy[14][c] = a2;
                        Lsxy[11][c] = b0; Lsxy[12][c] = b1; Lsxy[13][c] = b2; Lsxy[14][c] = b3;
                    }
                }
            }
        } else {
            // interior owned velocity: taps only owned LDS stress rows (verified
            // index ranges Lsyy 4..10 / Lsxy 4..10 for w=2..5) -> no flag needed.
            vrow(lane, ampsS + t, vy, vx, msyyy, msxyy, msxyx, msxxx, sxx,
                 w + 4, w + 3, w + 2, by, bx2, bxm12, buO_p, mrO, mkc2, smO,
                 Lsyy, Lsxy, Lvy, Lvx);
            if (hasG) {
                if ((w < 4) ? (j > 0) : (j < NSTRIP_ - 1)) {
                    const unsigned* fad = (w < 4) ? &flg[sbase + j - 1] : &flg[sbase + j + 1];
                    while (cldu(fad) < (unsigned)t) __builtin_amdgcn_s_sleep(1);
                }
                #pragma unroll
                for (int k = 0; k < 5; ++k) sxxE[k] = cld(rSxx + gyE * NX_ + 64 * k + lane);
            }
        }
        __syncthreads();   // (A) imports + interior V complete
        asm volatile("" ::: "memory");

        // ==== phase 2: edge waves owned V; interior waves ghost V (1 row/wave) ====
        if (isE) {
            vrow(lane, ampsS + t, vy, vx, msyyy, msxyy, msxyx, msxxx, sxx,
                 w + 4, w + 3, w + 2, by, bx2, bxm12, buO_p, mrO, mkc2, smO,
                 Lsyy, Lsxy, Lvy, Lvx);
        } else if (hasG) {
            vrow(lane, ampsS + t, vyE, vxE, msyyyE, msxyyE, msxyxE, msxxxE, sxxE,
                 lySE, lxSE, lvE, byE, bx2, bxm12, buE_p, mrE, mkc2, smE,
                 Lsyy, Lsxy, Lvy, Lvx);
        }
        __syncthreads();   // (B) all velocity rows -2..9 current

        // record receivers (strip-local)
        if (myrec) recp[t] = ((const float*)Lvy)[rl];

        // ==== phase 3: stress (all waves, owned rows) + inline publish ====
        {
            const int lv = w + 2;
            #pragma unroll
            for (int k = 0; k < 5; ++k) {
                const int c = 64 * k + lane;
                const bool px = (k == 0 || k == 4);
                const int xk = (k == 0) ? 0 : 1;
                const float mk = mrO * (px ? mkc2[xk] : 1.0f);
                const float lak = laO_p[c];
                const float muk = muO_p[c];
                float d, e1, e2, g;
                // D+_y(vy)
                d = (C1_ * (Lvy[lv + 1][c] - vy[k]) + C2_ * (Lvy[lv + 2][c] - Lvy[lv - 1][c])) * IDH_;
                mvyy[k] = by * mvyy[k] + bym1 * d;
                e1 = d + mvyy[k];
                // D-_x(vx)
                d = (C1_ * (vx[k] - ltap(Lvx, lv, c - 1))
                   + C2_ * (ltap(Lvx, lv, c + 1) - ltap(Lvx, lv, c - 2))) * IDH_;
                if (px) { mvxx[xk] = bx2[xk] * mvxx[xk] + bxm12[xk] * d; e2 = d + mvxx[xk]; }
                else    { e2 = d; }
                const float l2m = lak + 2.0f * muk;
                syy[k] = (syy[k] + DT_ * (l2m * e1 + lak * e2)) * mk;
                sxx[k] = (sxx[k] + DT_ * (l2m * e2 + lak * e1)) * mk;
                // D+_x(vy)
                d = (C1_ * (ltap(Lvy, lv, c + 1) - vy[k])
                   + C2_ * (ltap(Lvy, lv, c + 2) - ltap(Lvy, lv, c - 1))) * IDH_;
                if (px) { mvyx[xk] = bx2[xk] * mvyx[xk] + bxm12[xk] * d; g = d + mvyx[xk]; }
                else    { g = d; }
                // D-_y(vx)
                d = (C1_ * (vx[k] - Lvx[lv - 1][c]) + C2_ * (Lvx[lv + 1][c] - Lvx[lv - 2][c])) * IDH_;
                mvxy[k] = by * mvxy[k] + bym1 * d;
                g = g + d + mvxy[k];
                sxy[k] = (sxy[k] + DT_ * muk * g) * mk;
                Lsyy[w + 4][c] = syy[k];
                Lsxy[w + 3][c] = sxy[k];
                // publish exactly the rows neighbors import:
                // syy rows {0..7}\{3}, sxy {0..7}\{4}, sxx {0,1,6,7}
                if (w != 3) cst(&wSyy[gy * NX_ + c], syy[k]);
                if (w != 4) cst(&wSxy[gy * NX_ + c], sxy[k]);
                if (isE)    cst(&wSxx[gy * NX_ + c], sxx[k]);
            }
        }
        __syncthreads();   // (C) — each wave drains its vmcnt before s_barrier
        if (tid == 0) {
            asm volatile("s_waitcnt vmcnt(0)" ::: "memory");
            cstu(&flg[sbase + j], (unsigned)(t + 1));
        }
    }

    // ---------- final output: out[s][r][t] = 0.5*(rec[t] + rec[t+1]) ----------
    if (myrec) {
        float* op = out + (s * NREC_ + tid) * (NT_ - 1);
        for (int t = 0; t < NT_ - 1; ++t) op[t] = 0.5f * (recp[t] + recp[t + 1]);
    }
}

extern "C" void kernel_launch(void* const* d_in, const int* in_sizes, int n_in,
                              void* d_out, int out_size, void* d_ws, size_t ws_size,
                              hipStream_t stream)
{
    const float* lamb = (const float*)d_in[0];
    const float* mu   = (const float*)d_in[1];
    const float* buoy = (const float*)d_in[2];
    const float* amps = (const float*)d_in[3];
    const int*   src  = (const int*)d_in[4];
    const int*   recl = (const int*)d_in[5];
    float* out = (float*)d_out;
    float* ws  = (float*)d_ws;

    init_kernel<<<dim3(512), dim3(256), 0, stream>>>(ws);
    elastic_kernel<<<dim3(NBLK_), dim3(512), 0, stream>>>(lamb, mu, buoy, amps, src, recl, out, ws);
}

// Round 8
// 1324.363 us; speedup vs baseline: 2.0434x; 1.0153x over previous
//
#include <hip/hip_runtime.h>
#include <math.h>

constexpr int NY_ = 320, NX_ = 320, NT_ = 160, SHOTS_ = 2, NSRC_ = 8, NREC_ = 96;
constexpr float DT_  = 4.0e-4f;
constexpr float C1_  = 9.0f / 8.0f;
constexpr float C2_  = -1.0f / 24.0f;
constexpr float IDH_ = 0.25f;           // 1/DH, exact
constexpr int NP_     = NY_ * NX_;
constexpr int NSTRIP_ = 40;             // 8-row strips per shot
constexpr int NBLK_   = SHOTS_ * NSTRIP_;
// ws layout (float words): stress mirrors [buf2][field3: syy,sxy,sxx][shot2][NP],
// receiver traces, flags (monotonic round counters).
constexpr int REC_OFF_ = 12 * NP_;
constexpr int FLG_OFF_ = REC_OFF_ + SHOTS_ * NREC_ * NT_;
constexpr int WS_WORDS_ = FLG_OFF_ + 128;

// ---- coherent (IF-backed) access: relaxed agent-scope atomics ----
__device__ __forceinline__ float cld(const float* p) {
    return __hip_atomic_load(p, __ATOMIC_RELAXED, __HIP_MEMORY_SCOPE_AGENT);
}
__device__ __forceinline__ void cst(float* p, float v) {
    __hip_atomic_store(p, v, __ATOMIC_RELAXED, __HIP_MEMORY_SCOPE_AGENT);
}
__device__ __forceinline__ unsigned cldu(const unsigned* p) {
    return __hip_atomic_load(p, __ATOMIC_RELAXED, __HIP_MEMORY_SCOPE_AGENT);
}
__device__ __forceinline__ void cstu(unsigned* p, unsigned v) {
    __hip_atomic_store(p, v, __ATOMIC_RELAXED, __HIP_MEMORY_SCOPE_AGENT);
}

// guarded halo import load: out-of-grid rows read 0 (== masked border equivalence)
__device__ __forceinline__ float gldf(const float* p, int y, int c) {
    return ((unsigned)y < (unsigned)NY_) ? cld(p + y * NX_ + c) : 0.0f;
}
// guarded LDS x-tap: out-of-grid cols read 0
__device__ __forceinline__ float ltap(const float (*A)[NX_], int ly, int c) {
    return ((unsigned)c < (unsigned)NX_) ? A[ly][c] : 0.0f;
}
// register x-tap via wave shuffle (cells are 64-col interleaved, 5 groups/lane)
__device__ __forceinline__ float shtap(float cur, float adj, int lane, int dx) {
    int idx = (lane + dx) & 63;
    float a = __shfl(cur, idx, 64);
    float b = __shfl(adj, idx, 64);
    return ((unsigned)(lane + dx) < 64u) ? a : b;
}

__device__ __forceinline__ float pml_by(int gy) {
    const double d0 = 3.0 * 1600.0 * log(1000.0) / (2.0 * 20.0 * 4.0);
    double py = 0.0;
    if (gy < 20)             { double u = (20.0 - gy) / 20.0;           py = u * u; }
    else if (gy >= NY_ - 20) { double u = (gy - (NY_ - 1 - 20)) / 20.0; py = u * u; }
    return (float)exp(-d0 * py * 4.0e-4);
}

__device__ __forceinline__ unsigned long long srcmask(const int* __restrict__ src_loc,
                                                      int s, int gy, int lane) {
    unsigned long long sm = 0ull;
    if ((unsigned)gy < (unsigned)NY_) {
        for (int js = 0; js < NSRC_; ++js) {
            int sy = src_loc[(s * NSRC_ + js) * 2 + 0];
            int sx = src_loc[(s * NSRC_ + js) * 2 + 1];
            if (sy == gy && (sx & 63) == lane) sm |= 1ull << (8 * (sx >> 6) + js);
        }
    }
    return sm;
}

// x-CPML static sparsity: groups k=1,2,3 (cols 64..255) have bx=1 -> x memory vars
// stay exactly 0 forever -> packed [2] arrays hold only k=0,k=4. Bit-exact.

// ---- owned-row velocity + CPML update (self sxx in registers, shuffle x-taps) ----
__device__ __forceinline__ void vrow(
    int lane, const float* __restrict__ ampsT,
    float (&VY)[5], float (&VX)[5],
    float (&MS1)[5], float (&MS2)[5], float (&MS3)[2], float (&MS4)[2], // msyyy,msxyy,msxyx,msxxx
    const float (&SXX)[5],
    int lyS, int lxS, int lv,
    float by, const float (&bx2)[2], const float (&bxm12)[2],
    const float* __restrict__ buRow, float mr, const float (&mkc2)[2],
    unsigned long long sm,
    const float (*Lsyy)[NX_], const float (*Lsxy)[NX_],
    float (*Lvy)[NX_], float (*Lvx)[NX_])
{
    const float bym1 = by - 1.0f;
    #pragma unroll
    for (int k = 0; k < 5; ++k) {
        const int c = 64 * k + lane;
        const bool px = (k == 0 || k == 4);
        const int xk = (k == 0) ? 0 : 1;
        const float mk = mr * (px ? mkc2[xk] : 1.0f);
        const float buk = buRow[c];
        // D-_y(syy)
        float d = (C1_ * (Lsyy[lyS][c] - Lsyy[lyS - 1][c])
                 + C2_ * (Lsyy[lyS + 1][c] - Lsyy[lyS - 2][c])) * IDH_;
        MS1[k] = by * MS1[k] + bym1 * d;
        float ay = d + MS1[k];
        // D+_x(sxy)
        d = (C1_ * (ltap(Lsxy, lxS, c + 1) - Lsxy[lxS][c])
           + C2_ * (ltap(Lsxy, lxS, c + 2) - ltap(Lsxy, lxS, c - 1))) * IDH_;
        if (px) { MS3[xk] = bx2[xk] * MS3[xk] + bxm12[xk] * d; ay += d + MS3[xk]; }
        else    { ay += d; }
        VY[k] = VY[k] + DT_ * buk * ay;
        unsigned m = (unsigned)(sm >> (8 * k)) & 0xFFu;
        if (m) {
            for (int js = 0; js < NSRC_; ++js)
                if (m & (1u << js)) VY[k] += DT_ * ampsT[js * NT_] * buk;
        }
        VY[k] *= mk;
        // D-_x(sxx) via register shuffles
        const float sxxp = (k < 4) ? SXX[k + 1] : 0.0f;
        const float sxxm = (k > 0) ? SXX[k - 1] : 0.0f;
        d = (C1_ * (SXX[k] - shtap(SXX[k], sxxm, lane, -1))
           + C2_ * (shtap(SXX[k], sxxp, lane, 1) - shtap(SXX[k], sxxm, lane, -2))) * IDH_;
        float ax;
        if (px) { MS4[xk] = bx2[xk] * MS4[xk] + bxm12[xk] * d; ax = d + MS4[xk]; }
        else    { ax = d; }
        // D+_y(sxy)
        d = (C1_ * (Lsxy[lxS + 1][c] - Lsxy[lxS][c])
           + C2_ * (Lsxy[lxS + 2][c] - Lsxy[lxS - 1][c])) * IDH_;
        MS2[k] = by * MS2[k] + bym1 * d;
        ax += d + MS2[k];
        VX[k] = (VX[k] + DT_ * buk * ax) * mk;
        Lvy[lv][c] = VY[k]; Lvx[lv][c] = VX[k];
    }
}

// ---- ghost-row velocity + CPML update (sxx taps from LDS mirror row) ----
__device__ __forceinline__ void vrowG(
    int lane, const float* __restrict__ ampsT,
    float (&VY)[5], float (&VX)[5],
    float (&MS1)[5], float (&MS2)[5], float (&MS3)[2], float (&MS4)[2],
    const float (*SXXL)[NX_], int gr,
    int lyS, int lxS, int lv,
    float by, const float (&bx2)[2], const float (&bxm12)[2],
    const float* __restrict__ buRow, float mr, const float (&mkc2)[2],
    unsigned long long sm,
    const float (*Lsyy)[NX_], const float (*Lsxy)[NX_],
    float (*Lvy)[NX_], float (*Lvx)[NX_])
{
    const float bym1 = by - 1.0f;
    #pragma unroll
    for (int k = 0; k < 5; ++k) {
        const int c = 64 * k + lane;
        const bool px = (k == 0 || k == 4);
        const int xk = (k == 0) ? 0 : 1;
        const float mk = mr * (px ? mkc2[xk] : 1.0f);
        const float buk = buRow[c];
        // D-_y(syy)
        float d = (C1_ * (Lsyy[lyS][c] - Lsyy[lyS - 1][c])
                 + C2_ * (Lsyy[lyS + 1][c] - Lsyy[lyS - 2][c])) * IDH_;
        MS1[k] = by * MS1[k] + bym1 * d;
        float ay = d + MS1[k];
        // D+_x(sxy)
        d = (C1_ * (ltap(Lsxy, lxS, c + 1) - Lsxy[lxS][c])
           + C2_ * (ltap(Lsxy, lxS, c + 2) - ltap(Lsxy, lxS, c - 1))) * IDH_;
        if (px) { MS3[xk] = bx2[xk] * MS3[xk] + bxm12[xk] * d; ay += d + MS3[xk]; }
        else    { ay += d; }
        VY[k] = VY[k] + DT_ * buk * ay;
        unsigned m = (unsigned)(sm >> (8 * k)) & 0xFFu;
        if (m) {
            for (int js = 0; js < NSRC_; ++js)
                if (m & (1u << js)) VY[k] += DT_ * ampsT[js * NT_] * buk;
        }
        VY[k] *= mk;
        // D-_x(sxx) from LDS mirror row (identical values to the register path)
        d = (C1_ * (SXXL[gr][c] - ltap(SXXL, gr, c - 1))
           + C2_ * (ltap(SXXL, gr, c + 1) - ltap(SXXL, gr, c - 2))) * IDH_;
        float ax;
        if (px) { MS4[xk] = bx2[xk] * MS4[xk] + bxm12[xk] * d; ax = d + MS4[xk]; }
        else    { ax = d; }
        // D+_y(sxy)
        d = (C1_ * (Lsxy[lxS + 1][c] - Lsxy[lxS][c])
           + C2_ * (Lsxy[lxS + 2][c] - Lsxy[lxS - 1][c])) * IDH_;
        MS2[k] = by * MS2[k] + bym1 * d;
        ax += d + MS2[k];
        VX[k] = (VX[k] + DT_ * buk * ax) * mk;
        Lvy[lv][c] = VY[k]; Lvx[lv][c] = VX[k];
    }
}

__global__ void init_kernel(float* __restrict__ ws) {
    for (int i = blockIdx.x * 256 + threadIdx.x; i < WS_WORDS_; i += gridDim.x * 256)
        ws[i] = 0.0f;
}

__global__ __launch_bounds__(512)
void elastic_kernel(const float* __restrict__ lamb, const float* __restrict__ mu,
                    const float* __restrict__ buoy, const float* __restrict__ amps,
                    const int* __restrict__ src_loc, const int* __restrict__ rec_loc,
                    float* __restrict__ out, float* __restrict__ ws)
{
    // LDS row maps: Lvy/Lvx: y -> y+2 (rows -2..9)
    //               Lsyy:    y -> y+4 (rows -4..10)
    //               Lsxy:    y -> y+3 (rows -3..11)
    //               Lsxxg:   ghost sxx rows {-2,-1,8,9} -> {0,1,2,3}
    __shared__ float Lvy[12][NX_], Lvx[12][NX_], Lsyy[15][NX_], Lsxy[15][NX_], Lsxxg[4][NX_];

    const int tid  = threadIdx.x;
    const int lane = tid & 63;
    const int w    = tid >> 6;          // owned row 0..7 (one wave per row)
    const int bid  = blockIdx.x;
    const int s    = bid / NSTRIP_;
    const int j    = bid % NSTRIP_;
    const int r0   = j * 8;
    const int gy   = r0 + w;

    unsigned* flg = (unsigned*)(ws + FLG_OFF_);
    const int sbase = s * NSTRIP_;
    float* recp = ws + REC_OFF_ + (s * NREC_ + tid) * NT_;   // valid only if tid<96
    const float* ampsS = amps + s * NSRC_ * NT_;

    // role split: edge waves {0,1,6,7} poll + import the side halos (incl. ghost sxx);
    // interior waves {2..5} are fully flag-free (owned vrow, then ghost vrow from LDS).
    const bool isE = (w < 2) || (w >= 6);
    const bool top = (w < 2);
    // ghost rows (interior waves): w2..5 -> y {-2,-1,8,9}; Lsxxg row = w-2
    const int  yE  = (w < 4) ? (w - 4) : (w + 4);
    const int  gyE = r0 + yE;
    const bool hasG = (!isE) && ((unsigned)gyE < (unsigned)NY_);
    const int lySE = yE + 4, lxSE = yE + 3, lvE = yE + 2, grE = w - 2;
    const int cEr = hasG ? gyE : 0;

    // material row base pointers (wave-uniform -> SGPR; regular cached loads)
    const float* buO_p = buoy + gy * NX_;
    const float* laO_p = lamb + gy * NX_;
    const float* muO_p = mu   + gy * NX_;
    const float* buE_p = buoy + cEr * NX_;

    // per-row wave-uniform scalars
    const float by   = pml_by(gy);
    const float bym1 = by - 1.0f;
    const float byE  = pml_by(gyE);
    const float mrO  = (gy  >= 2 && gy  < NY_ - 2) ? 1.0f : 0.0f;
    const float mrE  = (gyE >= 2 && gyE < NY_ - 2) ? 1.0f : 0.0f;

    const double d0 = 3.0 * 1600.0 * log(1000.0) / (2.0 * 20.0 * 4.0);
    float bx2[2], bxm12[2], mkc2[2];
    #pragma unroll
    for (int e = 0; e < 2; ++e) {
        int c = (e == 0) ? lane : 256 + lane;   // groups k=0 and k=4
        double pxd = 0.0;
        if (c < 20)             { double u = (20.0 - c) / 20.0;           pxd = u * u; }
        else if (c >= NX_ - 20) { double u = (c - (NX_ - 1 - 20)) / 20.0; pxd = u * u; }
        bx2[e] = (float)exp(-d0 * pxd * 4.0e-4);
        bxm12[e] = bx2[e] - 1.0f;
        mkc2[e] = (c >= 2 && c < NX_ - 2) ? 1.0f : 0.0f;
    }

    const unsigned long long smO = srcmask(src_loc, s, gy, lane);
    const unsigned long long smE = hasG ? srcmask(src_loc, s, gyE, lane) : 0ull;

    // per-thread receiver (tid<96 handles receiver tid of this shot)
    bool myrec = false; int rl = 0;
    if (tid < NREC_) {
        int ry = rec_loc[(s * NREC_ + tid) * 2 + 0];
        int rx = rec_loc[(s * NREC_ + tid) * 2 + 1];
        if ((ry >> 3) == j) { myrec = true; rl = ((ry & 7) + 2) * NX_ + rx; }
    }

    // zero LDS (fields start at 0)
    for (int i = tid; i < 15 * NX_; i += 512) {
        if (i < 12 * NX_) { ((float*)Lvy)[i] = 0.f; ((float*)Lvx)[i] = 0.f; }
        if (i < 4 * NX_)  { ((float*)Lsxxg)[i] = 0.f; }
        ((float*)Lsyy)[i] = 0.f; ((float*)Lsxy)[i] = 0.f;
    }

    // ---- register state (x-CPML packed); ghost state lives in interior waves ----
    float vy[5] = {}, vx[5] = {}, syy[5] = {}, sxy[5] = {}, sxx[5] = {};
    float msyyy[5] = {}, msxyy[5] = {}, msxyx[2] = {}, msxxx[2] = {};
    float mvyy[5] = {}, mvyx[2] = {}, mvxy[5] = {}, mvxx[2] = {};
    float vyE[5] = {}, vxE[5] = {};
    float msyyyE[5] = {}, msxyyE[5] = {}, msxyxE[2] = {}, msxxxE[2] = {};

    __syncthreads();

    for (int t = 0; t < NT_; ++t) {
        const int rb = t & 1, wb = rb ^ 1;   // ping-pong stress mirrors, flag-gated
        const float* rSyy = ws + ((rb * 3 + 0) * SHOTS_ + s) * NP_;
        const float* rSxy = ws + ((rb * 3 + 1) * SHOTS_ + s) * NP_;
        const float* rSxx = ws + ((rb * 3 + 2) * SHOTS_ + s) * NP_;
        float* wSyy = ws + ((wb * 3 + 0) * SHOTS_ + s) * NP_;
        float* wSxy = ws + ((wb * 3 + 1) * SHOTS_ + s) * NP_;
        float* wSxx = ws + ((wb * 3 + 2) * SHOTS_ + s) * NP_;

        // ==== phase 1: {edge: poll side flag + BATCHED import of side halo (9 rows)}
        //           || {interior: owned velocity — no flags, no global loads} ====
        if (isE) {
            if (top ? (j > 0) : (j < NSTRIP_ - 1)) {
                const unsigned* fad = top ? &flg[sbase + j - 1] : &flg[sbase + j + 1];
                while (cldu(fad) < (unsigned)t) __builtin_amdgcn_s_sleep(1);
            }
            const int tp = tid & 127;   // 0..127 across the side's two waves
            // ---- all 27 loads issued before any LDS write: ONE round-trip ----
            float A[3][9];
            #pragma unroll
            for (int i = 0; i < 3; ++i) {
                const int c = tp + 128 * i;
                const bool okc = (c < NX_);
                if (top) {
                    A[i][0] = okc ? gldf(rSyy, r0 - 4, c) : 0.f;
                    A[i][1] = okc ? gldf(rSyy, r0 - 3, c) : 0.f;
                    A[i][2] = okc ? gldf(rSyy, r0 - 2, c) : 0.f;
                    A[i][3] = okc ? gldf(rSyy, r0 - 1, c) : 0.f;
                    A[i][4] = okc ? gldf(rSxy, r0 - 3, c) : 0.f;
                    A[i][5] = okc ? gldf(rSxy, r0 - 2, c) : 0.f;
                    A[i][6] = okc ? gldf(rSxy, r0 - 1, c) : 0.f;
                    A[i][7] = okc ? gldf(rSxx, r0 - 2, c) : 0.f;
                    A[i][8] = okc ? gldf(rSxx, r0 - 1, c) : 0.f;
                } else {
                    A[i][0] = okc ? gldf(rSyy, r0 + 8, c)  : 0.f;
                    A[i][1] = okc ? gldf(rSyy, r0 + 9, c)  : 0.f;
                    A[i][2] = okc ? gldf(rSyy, r0 + 10, c) : 0.f;
                    A[i][3] = okc ? gldf(rSxy, r0 + 8, c)  : 0.f;
                    A[i][4] = okc ? gldf(rSxy, r0 + 9, c)  : 0.f;
                    A[i][5] = okc ? gldf(rSxy, r0 + 10, c) : 0.f;
                    A[i][6] = okc ? gldf(rSxy, r0 + 11, c) : 0.f;
                    A[i][7] = okc ? gldf(rSxx, r0 + 8, c)  : 0.f;
                    A[i][8] = okc ? gldf(rSxx, r0 + 9, c)  : 0.f;
                }
            }
            #pragma unroll
            for (int i = 0; i < 3; ++i) {
                const int c = tp + 128 * i;
                if (c < NX_) {
                    if (top) {
                        Lsyy[0][c] = A[i][0]; Lsyy[1][c] = A[i][1];
                        Lsyy[2][c] = A[i][2]; Lsyy[3][c] = A[i][3];
                        Lsxy[0][c] = A[i][4]; Lsxy[1][c] = A[i][5]; Lsxy[2][c] = A[i][6];
                        Lsxxg[0][c] = A[i][7]; Lsxxg[1][c] = A[i][8];
                    } else {
                        Lsyy[12][c] = A[i][0]; Lsyy[13][c] = A[i][1]; Lsyy[14][c] = A[i][2];
                        Lsxy[11][c] = A[i][3]; Lsxy[12][c] = A[i][4];
                        Lsxy[13][c] = A[i][5]; Lsxy[14][c] = A[i][6];
                        Lsxxg[2][c] = A[i][7]; Lsxxg[3][c] = A[i][8];
                    }
                }
            }
        } else {
            // interior owned velocity: taps only owned LDS stress rows (Lsyy/Lsxy
            // indices 4..10 for w=2..5, all strip-local) -> flag-free.
            vrow(lane, ampsS + t, vy, vx, msyyy, msxyy, msxyx, msxxx, sxx,
                 w + 4, w + 3, w + 2, by, bx2, bxm12, buO_p, mrO, mkc2, smO,
                 Lsyy, Lsxy, Lvy, Lvx);
        }
        __syncthreads();   // (A) imports + interior V complete
        asm volatile("" ::: "memory");

        // ==== phase 2: edge waves owned V; interior waves ghost V (1 row/wave) ====
        if (isE) {
            vrow(lane, ampsS + t, vy, vx, msyyy, msxyy, msxyx, msxxx, sxx,
                 w + 4, w + 3, w + 2, by, bx2, bxm12, buO_p, mrO, mkc2, smO,
                 Lsyy, Lsxy, Lvy, Lvx);
        } else if (hasG) {
            vrowG(lane, ampsS + t, vyE, vxE, msyyyE, msxyyE, msxyxE, msxxxE,
                  Lsxxg, grE, lySE, lxSE, lvE, byE, bx2, bxm12, buE_p, mrE, mkc2, smE,
                  Lsyy, Lsxy, Lvy, Lvx);
        }
        __syncthreads();   // (B) all velocity rows -2..9 current

        // record receivers (strip-local)
        if (myrec) recp[t] = ((const float*)Lvy)[rl];

        // ==== phase 3: stress (all waves, owned rows) + inline publish ====
        {
            const int lv = w + 2;
            #pragma unroll
            for (int k = 0; k < 5; ++k) {
                const int c = 64 * k + lane;
                const bool px = (k == 0 || k == 4);
                const int xk = (k == 0) ? 0 : 1;
                const float mk = mrO * (px ? mkc2[xk] : 1.0f);
                const float lak = laO_p[c];
                const float muk = muO_p[c];
                float d, e1, e2, g;
                // D+_y(vy)
                d = (C1_ * (Lvy[lv + 1][c] - vy[k]) + C2_ * (Lvy[lv + 2][c] - Lvy[lv - 1][c])) * IDH_;
                mvyy[k] = by * mvyy[k] + bym1 * d;
                e1 = d + mvyy[k];
                // D-_x(vx)
                d = (C1_ * (vx[k] - ltap(Lvx, lv, c - 1))
                   + C2_ * (ltap(Lvx, lv, c + 1) - ltap(Lvx, lv, c - 2))) * IDH_;
                if (px) { mvxx[xk] = bx2[xk] * mvxx[xk] + bxm12[xk] * d; e2 = d + mvxx[xk]; }
                else    { e2 = d; }
                const float l2m = lak + 2.0f * muk;
                syy[k] = (syy[k] + DT_ * (l2m * e1 + lak * e2)) * mk;
                sxx[k] = (sxx[k] + DT_ * (l2m * e2 + lak * e1)) * mk;
                // D+_x(vy)
                d = (C1_ * (ltap(Lvy, lv, c + 1) - vy[k])
                   + C2_ * (ltap(Lvy, lv, c + 2) - ltap(Lvy, lv, c - 1))) * IDH_;
                if (px) { mvyx[xk] = bx2[xk] * mvyx[xk] + bxm12[xk] * d; g = d + mvyx[xk]; }
                else    { g = d; }
                // D-_y(vx)
                d = (C1_ * (vx[k] - Lvx[lv - 1][c]) + C2_ * (Lvx[lv + 1][c] - Lvx[lv - 2][c])) * IDH_;
                mvxy[k] = by * mvxy[k] + bym1 * d;
                g = g + d + mvxy[k];
                sxy[k] = (sxy[k] + DT_ * muk * g) * mk;
                Lsyy[w + 4][c] = syy[k];
                Lsxy[w + 3][c] = sxy[k];
                // publish exactly the rows neighbors import:
                // syy rows {0..7}\{3}, sxy {0..7}\{4}, sxx {0,1,6,7}
                if (w != 3) cst(&wSyy[gy * NX_ + c], syy[k]);
                if (w != 4) cst(&wSxy[gy * NX_ + c], sxy[k]);
                if (isE)    cst(&wSxx[gy * NX_ + c], sxx[k]);
            }
        }
        __syncthreads();   // (C) — each wave drains its vmcnt before s_barrier
        if (tid == 0) {
            asm volatile("s_waitcnt vmcnt(0)" ::: "memory");
            cstu(&flg[sbase + j], (unsigned)(t + 1));
        }
    }

    // ---------- final output: out[s][r][t] = 0.5*(rec[t] + rec[t+1]) ----------
    if (myrec) {
        float* op = out + (s * NREC_ + tid) * (NT_ - 1);
        for (int t = 0; t < NT_ - 1; ++t) op[t] = 0.5f * (recp[t] + recp[t + 1]);
    }
}

extern "C" void kernel_launch(void* const* d_in, const int* in_sizes, int n_in,
                              void* d_out, int out_size, void* d_ws, size_t ws_size,
                              hipStream_t stream)
{
    const float* lamb = (const float*)d_in[0];
    const float* mu   = (const float*)d_in[1];
    const float* buoy = (const float*)d_in[2];
    const float* amps = (const float*)d_in[3];
    const int*   src  = (const int*)d_in[4];
    const int*   recl = (const int*)d_in[5];
    float* out = (float*)d_out;
    float* ws  = (float*)d_ws;

    init_kernel<<<dim3(512), dim3(256), 0, stream>>>(ws);
    elastic_kernel<<<dim3(NBLK_), dim3(512), 0, stream>>>(lamb, mu, buoy, amps, src, recl, out, ws);
}